// Round 7
// baseline (350.834 us; speedup 1.0000x reference)
//
#include <hip/hip_runtime.h>
#include <stdint.h>

#define DMODEL 1024
#define NHEAD 16
#define DH 64
#define BB 4
#define SS 2048
#define MROWS (BB * SS)   // 8192

typedef __bf16 bfx8 __attribute__((ext_vector_type(8)));
typedef float f32x4 __attribute__((ext_vector_type(4)));
typedef float fvec4 __attribute__((ext_vector_type(4)));
typedef int i32x4 __attribute__((ext_vector_type(4)));
typedef unsigned short u16x8 __attribute__((ext_vector_type(8)));

__device__ __forceinline__ unsigned short f2bf(float f) {
    union { float f; unsigned int u; } v; v.f = f;
    unsigned int r = v.u + 0x7FFFu + ((v.u >> 16) & 1u);
    return (unsigned short)(r >> 16);
}

__device__ __forceinline__ unsigned int cvtpk(float lo, float hi) {
    unsigned int r;
    asm("v_cvt_pk_bf16_f32 %0, %1, %2" : "=v"(r) : "v"(lo), "v"(hi));
    return r;
}

typedef __attribute__((address_space(1))) const void gas_t;
typedef __attribute__((address_space(3))) void las_t;
__device__ __forceinline__ void gload_lds16(const void* g, void* l) {
    __builtin_amdgcn_global_load_lds((gas_t*)g, (las_t*)l, 16, 0, 0);
}

__device__ __forceinline__ void hard_barrier() {
    __builtin_amdgcn_sched_barrier(0);
    __builtin_amdgcn_s_barrier();
    __builtin_amdgcn_sched_barrier(0);
}

// sigma: i bits [nf1 nf0 lg1 lg0 r1 r0] -> [nf1 lg1 lg0 nf0 r1 r0]
__device__ __forceinline__ int sigma_k(int i) {
    return (i & 0x20) | ((i & 0x0C) << 1) | ((i & 0x10) >> 2) | (i & 3);
}

// ---------------------------------------------------------------------------
// fp32 -> bf16 convert for q,k,v in one launch
// ---------------------------------------------------------------------------
__global__ void cvt3_kernel(const float* __restrict__ s0, const float* __restrict__ s1,
                            const float* __restrict__ s2,
                            unsigned short* __restrict__ d0, unsigned short* __restrict__ d1,
                            unsigned short* __restrict__ d2, int n8)
{
    const float* s = (blockIdx.y == 0) ? s0 : (blockIdx.y == 1) ? s1 : s2;
    unsigned short* d = (blockIdx.y == 0) ? d0 : (blockIdx.y == 1) ? d1 : d2;
    int i = blockIdx.x * blockDim.x + threadIdx.x;
    if (i >= n8) return;
    fvec4 a = *reinterpret_cast<const fvec4*>(&s[(size_t)i * 8]);
    fvec4 b = *reinterpret_cast<const fvec4*>(&s[(size_t)i * 8 + 4]);
    u16x8 o;
    #pragma unroll
    for (int j = 0; j < 4; ++j) { o[j] = f2bf(a[j]); o[j + 4] = f2bf(b[j]); }
    *reinterpret_cast<u16x8*>(&d[(size_t)i * 8]) = o;
}

// ---------------------------------------------------------------------------
// Transpose + convert: Wt[n][k] (bf16) = W[k][n] (fp32). 64x64 tiles.
// ---------------------------------------------------------------------------
__global__ void transpose_cvt3_kernel(const float* __restrict__ W0, unsigned short* __restrict__ T0,
                                      const float* __restrict__ W1, unsigned short* __restrict__ T1,
                                      const float* __restrict__ W2, unsigned short* __restrict__ T2)
{
    const float* W = (blockIdx.z == 0) ? W0 : (blockIdx.z == 1) ? W1 : W2;
    unsigned short* Wt = (blockIdx.z == 0) ? T0 : (blockIdx.z == 1) ? T1 : T2;
    __shared__ unsigned short t[64][72];
    const int tid = threadIdx.x;
    const int r0 = blockIdx.y * 64, c0 = blockIdx.x * 64;
    #pragma unroll
    for (int i = 0; i < 4; ++i) {
        int idx = tid + i * 256;
        int r = idx >> 4, c4 = idx & 15;
        fvec4 v = *reinterpret_cast<const fvec4*>(&W[(size_t)(r0 + r) * DMODEL + c0 + c4 * 4]);
        #pragma unroll
        for (int j = 0; j < 4; ++j) t[c4 * 4 + j][r] = f2bf(v[j]);
    }
    __syncthreads();
    #pragma unroll
    for (int i = 0; i < 2; ++i) {
        int idx = tid + i * 256;
        int r = idx >> 3, c8 = idx & 7;
        u16x8 v = *reinterpret_cast<const u16x8*>(&t[r][c8 * 8]);
        *reinterpret_cast<u16x8*>(&Wt[(size_t)(c0 + r) * DMODEL + r0 + c8 * 8]) = v;
    }
}

// ---------------------------------------------------------------------------
// Prepack K and V into swizzled 8KB LDS-image tiles per (bh, kt).
// z=0: Kp row i = Kproj row kt*64+sigma(i), chunk c at pos c^(i&7).
// z=1: Vp row d (transposed), chunk p holds k-chunk p^(d&7).
// ---------------------------------------------------------------------------
__global__ void prep_kernel(const unsigned short* __restrict__ Kb,
                            unsigned short* __restrict__ Kp,
                            const unsigned short* __restrict__ Vb,
                            unsigned short* __restrict__ Vp)
{
    __shared__ unsigned short t[64][72];
    const int tid = threadIdx.x;
    const int kt = blockIdx.x, bh = blockIdx.y;
    const int b = bh >> 4, h = bh & 15;
    const size_t tbase = ((size_t)bh * 32 + kt) * 4096;
    if (blockIdx.z == 0) {
        #pragma unroll
        for (int i = 0; i < 2; ++i) {
            int idx = tid + i * 256;
            int r = idx >> 3, c = idx & 7;
            u16x8 v = *reinterpret_cast<const u16x8*>(
                &Kb[((size_t)b * SS + kt * 64 + sigma_k(r)) * DMODEL + h * DH + c * 8]);
            *reinterpret_cast<u16x8*>(&Kp[tbase + r * 64 + ((c ^ (r & 7)) * 8)]) = v;
        }
    } else {
        #pragma unroll
        for (int i = 0; i < 2; ++i) {
            int idx = tid + i * 256;
            int sr = idx >> 3, c8 = idx & 7;
            u16x8 v = *reinterpret_cast<const u16x8*>(
                &Vb[((size_t)b * SS + kt * 64 + sr) * DMODEL + h * DH + c8 * 8]);
            #pragma unroll
            for (int j = 0; j < 8; ++j) t[c8 * 8 + j][sr] = v[j];
        }
        __syncthreads();
        #pragma unroll
        for (int i = 0; i < 2; ++i) {
            int idx = tid + i * 256;
            int dr = idx >> 3, p = idx & 7;
            int srcc = p ^ (dr & 7);
            u16x8 v = *reinterpret_cast<const u16x8*>(&t[dr][srcc * 8]);
            *reinterpret_cast<u16x8*>(&Vp[tbase + dr * 64 + p * 8]) = v;
        }
    }
}

// ---------------------------------------------------------------------------
// GEMM: out = A @ Bt^T + bias; bf16 in via global_load_lds.
// 128x128 tile, BK=64, 4 waves. blockIdx.z picks arg set.
// ---------------------------------------------------------------------------
struct GArg {
    const unsigned short* A;
    const unsigned short* Bt;
    const float* bias;
    void* O;
    float osc;
};

template<bool OUT_BF16>
__global__ __launch_bounds__(256, 2)
void gemm_kernel(GArg g0, GArg g1, int M, int N, int K)
{
    const GArg g = blockIdx.z ? g1 : g0;
    __shared__ unsigned short sA[128 * 64];
    __shared__ unsigned short sB[128 * 64];
    const int tid  = threadIdx.x;
    const int lane = tid & 63;
    const int wave = tid >> 6;
    const int wm = (wave >> 1) * 64, wn = (wave & 1) * 64;
    const int m0 = blockIdx.x * 128, n0 = blockIdx.y * 128;
    const int lr = lane & 15;
    const int lg = lane >> 4;

    f32x4 acc[4][4] = {};

    for (int kk0 = 0; kk0 < K; kk0 += 64) {
        __syncthreads();
        #pragma unroll
        for (int i = 0; i < 4; ++i) {
            int c = tid + i * 256;
            int row = c >> 3, col8 = c & 7;
            gload_lds16(&g.A[(size_t)(m0 + row) * K + kk0 + col8 * 8], &sA[c * 8]);
        }
        #pragma unroll
        for (int i = 0; i < 4; ++i) {
            int c = tid + i * 256;
            int row = c >> 3, col8 = c & 7;
            gload_lds16(&g.Bt[(size_t)(n0 + row) * K + kk0 + col8 * 8], &sB[c * 8]);
        }
        __syncthreads();

        bfx8 af[4][2], bfr[4][2];
        #pragma unroll
        for (int m = 0; m < 4; ++m)
            #pragma unroll
            for (int kk = 0; kk < 2; ++kk)
                af[m][kk] = *reinterpret_cast<const bfx8*>(
                    &sA[(wm + m * 16 + lr) * 64 + kk * 32 + lg * 8]);
        #pragma unroll
        for (int n = 0; n < 4; ++n)
            #pragma unroll
            for (int kk = 0; kk < 2; ++kk)
                bfr[n][kk] = *reinterpret_cast<const bfx8*>(
                    &sB[(wn + n * 16 + lr) * 64 + kk * 32 + lg * 8]);
        #pragma unroll
        for (int kk = 0; kk < 2; ++kk)
            #pragma unroll
            for (int m = 0; m < 4; ++m)
                #pragma unroll
                for (int n = 0; n < 4; ++n)
                    acc[m][n] = __builtin_amdgcn_mfma_f32_16x16x32_bf16(
                        af[m][kk], bfr[n][kk], acc[m][n], 0, 0, 0);
    }

    #pragma unroll
    for (int n = 0; n < 4; ++n) {
        int col = n0 + wn + n * 16 + lr;
        float bv = g.bias[col];
        #pragma unroll
        for (int m = 0; m < 4; ++m) {
            int rowb = m0 + wm + m * 16 + lg * 4;
            #pragma unroll
            for (int r = 0; r < 4; ++r) {
                float val = (acc[m][n][r] + bv) * g.osc;
                if (OUT_BF16)
                    ((unsigned short*)g.O)[(size_t)(rowb + r) * N + col] = f2bf(val);
                else
                    ((float*)g.O)[(size_t)(rowb + r) * N + col] = val;
            }
        }
    }
}

// ---------------------------------------------------------------------------
// Flash-style causal attention, merged q-tile pair per block.
// Q pre-scaled by 1/sqrt(2048)*log2(e). Kp/Vp: prepacked swizzled tiles.
// Grid: 1024 linear; bh = (g&7)*8 + g>>7 (XCD-clustered), pr = (g>>3)&15.
// Block = 128 thr = 2 waves x 32 q-rows, q-tiles {31-pr, pr}: one k-tile walk
// t=0..31-pr serves BOTH (state B only while t<=pr). Balanced 33 computes.
// Pipeline: 2-deep counted vmcnt, never drained in steady state.
// ---------------------------------------------------------------------------
__global__ __launch_bounds__(128, 2)
void attn_kernel(const unsigned short* __restrict__ Q,
                 const unsigned short* __restrict__ Kp,
                 const unsigned short* __restrict__ Vp,
                 unsigned short* __restrict__ C)
{
    __shared__ unsigned short lds[2][8192];   // per buf: [0,4096)=K, [4096,8192)=V

    const int tid  = threadIdx.x;
    const int lane = tid & 63;
    const int wave = tid >> 6;                // 0..1
    const int lr = lane & 15, lg = lane >> 4;
    const int g  = blockIdx.x;                // 0..1023
    const int bh = ((g & 7) << 3) | (g >> 7);
    const int pr = (g >> 3) & 15;
    const int qtA = 31 - pr, qtB = pr;
    const int b = bh >> 4, h = bh & 15;
    const size_t rowbase = (size_t)b * SS;
    const int hcol = h * DH;
    const int p0 = lg ^ (lr & 7);
    const size_t kvbase = (size_t)bh * 32 * 4096;

    const u16x8 onesu = {0x3F80, 0x3F80, 0x3F80, 0x3F80, 0x3F80, 0x3F80, 0x3F80, 0x3F80};
    union { u16x8 u; bfx8 b; } onesc; onesc.u = onesu;
    const bfx8 ones = onesc.b;

    // Q fragments for both q-tiles
    bfx8 aqA[2][2], aqB[2][2];
    #pragma unroll
    for (int m = 0; m < 2; ++m) {
        int qrA = qtA * 64 + wave * 32 + m * 16 + lr;
        const unsigned short* pA = &Q[(rowbase + qrA) * DMODEL + hcol + lg * 8];
        aqA[m][0] = *reinterpret_cast<const bfx8*>(pA);
        aqA[m][1] = *reinterpret_cast<const bfx8*>(pA + 32);
        int qrB = qtB * 64 + wave * 32 + m * 16 + lr;
        const unsigned short* pB = &Q[(rowbase + qrB) * DMODEL + hcol + lg * 8];
        aqB[m][0] = *reinterpret_cast<const bfx8*>(pB);
        aqB[m][1] = *reinterpret_cast<const bfx8*>(pB + 32);
    }

    f32x4 accoA[2][4] = {}, accoB[2][4] = {};
    f32x4 acclA[2] = {}, acclB[2] = {};
    float mrunA[2] = {0.f, 0.f}, mrunB[2] = {0.f, 0.f};
    bool mzA = true, mzB = true;

    auto stage = [&](int t, int buf) {
        const size_t tb = kvbase + (size_t)t * 4096;
        #pragma unroll
        for (int j = 0; j < 4; ++j) {
            gload_lds16(&Kp[tb + tid * 8 + j * 1024], &lds[buf][tid * 8 + j * 1024]);
            gload_lds16(&Vp[tb + tid * 8 + j * 1024], &lds[buf][4096 + tid * 8 + j * 1024]);
        }
    };

    auto compute = [&](int k0, int q0, bfx8 (&aq)[2][2], f32x4 (&acc_o)[2][4],
                       f32x4 (&acc_l)[2], float (&m_run)[2], bool& mz,
                       const unsigned short* kb, const unsigned short* vb) {
        // ---- S^T = K_perm @ Q
        f32x4 sc[2][4];
        #pragma unroll
        for (int nf = 0; nf < 4; ++nf) {
            int i = nf * 16 + lr;
            bfx8 ak0 = *reinterpret_cast<const bfx8*>(&kb[i * 64 + p0 * 8]);
            bfx8 ak1 = *reinterpret_cast<const bfx8*>(&kb[i * 64 + (p0 ^ 4) * 8]);
            #pragma unroll
            for (int m = 0; m < 2; ++m) {
                f32x4 s = {0.f, 0.f, 0.f, 0.f};
                s = __builtin_amdgcn_mfma_f32_16x16x32_bf16(ak0, aq[m][0], s, 0, 0, 0);
                s = __builtin_amdgcn_mfma_f32_16x16x32_bf16(ak1, aq[m][1], s, 0, 0, 0);
                sc[m][nf] = s;
            }
        }
        // ---- causal mask (diagonal-overlapping tiles only)
        #pragma unroll
        for (int m = 0; m < 2; ++m) {
            if (k0 + 63 > q0 + wave * 32 + m * 16) {
                int qrow = q0 + wave * 32 + m * 16 + lr;
                #pragma unroll
                for (int nf = 0; nf < 4; ++nf) {
                    int kb_ = k0 + ((nf >> 1) << 5) + (lg << 3) + ((nf & 1) << 2);
                    #pragma unroll
                    for (int r = 0; r < 4; ++r)
                        if (kb_ + r > qrow) sc[m][nf][r] = -3.0e38f;
                }
            }
        }
        // ---- softmax: defer-max fast path (exp2 domain)
        float pmax = -3.0e38f;
        #pragma unroll
        for (int m = 0; m < 2; ++m)
            #pragma unroll
            for (int nf = 0; nf < 4; ++nf) {
                float a = fmaxf(fmaxf(sc[m][nf][0], sc[m][nf][1]),
                                fmaxf(sc[m][nf][2], sc[m][nf][3]));
                pmax = fmaxf(pmax, a);
            }
        if (mz && __all(pmax <= 8.0f)) {
            #pragma unroll
            for (int m = 0; m < 2; ++m)
                #pragma unroll
                for (int nf = 0; nf < 4; ++nf)
                    #pragma unroll
                    for (int r = 0; r < 4; ++r)
                        sc[m][nf][r] = __builtin_exp2f(sc[m][nf][r]);
        } else {
            mz = false;
            #pragma unroll
            for (int m = 0; m < 2; ++m) {
                float mx = -3.0e38f;
                #pragma unroll
                for (int nf = 0; nf < 4; ++nf)
                    #pragma unroll
                    for (int r = 0; r < 4; ++r) mx = fmaxf(mx, sc[m][nf][r]);
                mx = fmaxf(mx, __shfl_xor(mx, 16, 64));
                mx = fmaxf(mx, __shfl_xor(mx, 32, 64));
                float mnew = fmaxf(m_run[m], mx);
                float fs = __builtin_exp2f(m_run[m] - mnew);
                m_run[m] = mnew;
                #pragma unroll
                for (int nf = 0; nf < 4; ++nf)
                    #pragma unroll
                    for (int r = 0; r < 4; ++r)
                        sc[m][nf][r] = __builtin_exp2f(sc[m][nf][r] - mnew);
                #pragma unroll
                for (int r = 0; r < 4; ++r) {
                    float fsa = __shfl(fs, lg * 4 + r, 64);
                    #pragma unroll
                    for (int d = 0; d < 4; ++d) acc_o[m][d][r] *= fsa;
                    acc_l[m][r] *= fsa;
                }
            }
        }
        // ---- pack P in-register; PV + l via MFMA
        #pragma unroll
        for (int h2 = 0; h2 < 2; ++h2) {
            union { i32x4 i; bfx8 b; } pa[2];
            #pragma unroll
            for (int m = 0; m < 2; ++m) {
                pa[m].i[0] = cvtpk(sc[m][2 * h2][0],     sc[m][2 * h2][1]);
                pa[m].i[1] = cvtpk(sc[m][2 * h2][2],     sc[m][2 * h2][3]);
                pa[m].i[2] = cvtpk(sc[m][2 * h2 + 1][0], sc[m][2 * h2 + 1][1]);
                pa[m].i[3] = cvtpk(sc[m][2 * h2 + 1][2], sc[m][2 * h2 + 1][3]);
            }
            acc_l[0] = __builtin_amdgcn_mfma_f32_16x16x32_bf16(pa[0].b, ones, acc_l[0], 0, 0, 0);
            acc_l[1] = __builtin_amdgcn_mfma_f32_16x16x32_bf16(pa[1].b, ones, acc_l[1], 0, 0, 0);
            #pragma unroll
            for (int d = 0; d < 4; ++d) {
                int dd = d * 16 + lr;
                int pv = ((h2 << 2) | lg) ^ (lr & 7);
                bfx8 bv = *reinterpret_cast<const bfx8*>(&vb[dd * 64 + pv * 8]);
                acc_o[0][d] = __builtin_amdgcn_mfma_f32_16x16x32_bf16(pa[0].b, bv, acc_o[0][d], 0, 0, 0);
                acc_o[1][d] = __builtin_amdgcn_mfma_f32_16x16x32_bf16(pa[1].b, bv, acc_o[1][d], 0, 0, 0);
            }
        }
    };

    const int ntiles = qtA + 1;               // >= 17
    stage(0, 0);
    stage(1, 1);
    for (int t = 0; t < ntiles; ++t) {
        if (t + 1 < ntiles) { asm volatile("s_waitcnt vmcnt(8)" ::: "memory"); }
        else                { asm volatile("s_waitcnt vmcnt(0)" ::: "memory"); }
        hard_barrier();
        const unsigned short* kb = &lds[t & 1][0];
        const unsigned short* vb = &lds[t & 1][4096];
        const int k0 = t * 64;
        compute(k0, qtA * 64, aqA, accoA, acclA, mrunA, mzA, kb, vb);
        if (t <= qtB)
            compute(k0, qtB * 64, aqB, accoB, acclB, mrunB, mzB, kb, vb);
        hard_barrier();
        if (t + 2 < ntiles) stage(t + 2, t & 1);
    }

    auto epi = [&](int q0, f32x4 (&acc_o)[2][4], f32x4 (&acc_l)[2]) {
        #pragma unroll
        for (int m = 0; m < 2; ++m) {
            const int qrb = q0 + wave * 32 + m * 16 + lg * 4;
            f32x4 linv;
            #pragma unroll
            for (int r = 0; r < 4; ++r) linv[r] = 1.0f / acc_l[m][r];
            #pragma unroll
            for (int d = 0; d < 4; ++d) {
                int col = hcol + d * 16 + lr;
                #pragma unroll
                for (int r = 0; r < 4; ++r)
                    C[(rowbase + qrb + r) * DMODEL + col] = f2bf(acc_o[m][d][r] * linv[r]);
            }
        }
    };
    epi(qtA * 64, accoA, acclA);
    epi(qtB * 64, accoB, acclB);
}

// ---------------------------------------------------------------------------
extern "C" void kernel_launch(void* const* d_in, const int* in_sizes, int n_in,
                              void* d_out, int out_size, void* d_ws, size_t ws_size,
                              hipStream_t stream)
{
    const float* q  = (const float*)d_in[0];
    const float* k  = (const float*)d_in[1];
    const float* v  = (const float*)d_in[2];
    const float* Wq = (const float*)d_in[3];
    const float* bq = (const float*)d_in[4];
    const float* Wk = (const float*)d_in[5];
    const float* bk = (const float*)d_in[6];
    const float* Wv = (const float*)d_in[7];
    const float* bv = (const float*)d_in[8];
    const float* Wf = (const float*)d_in[9];
    const float* bf = (const float*)d_in[10];

    unsigned short* ws = (unsigned short*)d_ws;
    const size_t SZ = (size_t)MROWS * DMODEL;        // 8388608 elems
    unsigned short* ws0 = ws;                        // qb16 -> Vproj -> Cb
    unsigned short* ws1 = ws + SZ;                   // kb16 -> Kp
    unsigned short* ws2 = ws + 2 * SZ;               // vb16 -> Vp
    unsigned short* ws3 = ws + 3 * SZ;               // Kproj -> WfT

    unsigned short* scr = (unsigned short*)d_out;    // d_out as scratch
    unsigned short* WqT = scr;                       // [0,1M)
    unsigned short* WkT = scr + 1048576;             // [1M,2M)
    unsigned short* WvT = scr + 2097152;             // [2M,3M)
    unsigned short* Qb  = scr + 4194304;             // [4M,12M)

    const float qscale = 0.02209708691207961f * 1.44269504088896341f;

    // 1. q,k,v fp32 -> bf16
    const int n8 = (int)(SZ / 8);
    cvt3_kernel<<<dim3((n8 + 255) / 256, 3), 256, 0, stream>>>(q, k, v, ws0, ws1, ws2, n8);

    // 2. Wq/Wk/Wv transpose
    transpose_cvt3_kernel<<<dim3(16, 16, 3), 256, 0, stream>>>(Wq, WqT, Wk, WkT, Wv, WvT);

    // 3. Q and K projections (Q pre-scaled into exp2 domain)
    {
        GArg gq{ws0, WqT, bq, Qb,  qscale};
        GArg gk{ws1, WkT, bk, ws3, 1.0f};
        gemm_kernel<true><<<dim3(64, 8, 2), 256, 0, stream>>>(gq, gk, MROWS, DMODEL, DMODEL);
    }
    // 4. V projection -> ws0 (qb16 dead)
    {
        GArg gv{ws2, WvT, bv, ws0, 1.0f};
        gemm_kernel<true><<<dim3(64, 8, 1), 256, 0, stream>>>(gv, gv, MROWS, DMODEL, DMODEL);
    }
    // 5. prepack K (ws3 -> ws1, kb16 dead) and V (ws0 -> ws2, vb16 dead)
    prep_kernel<<<dim3(SS / 64, BB * NHEAD, 2), 256, 0, stream>>>(ws3, ws1, ws0, ws2);

    // 6. Wf transpose -> ws3 (Kproj dead)
    transpose_cvt3_kernel<<<dim3(16, 16, 1), 256, 0, stream>>>(Wf, ws3, Wf, ws3, Wf, ws3);

    // 7. attention: Qb, Kp(ws1), Vp(ws2) -> Cb(ws0)  (Vproj dead)
    attn_kernel<<<dim3(1024), 128, 0, stream>>>(Qb, ws1, ws2, ws0);

    // 8. output projection: Cb @ WfT + bf -> d_out fp32
    {
        GArg gf{ws0, ws3, bf, (float*)d_out, 1.0f};
        gemm_kernel<false><<<dim3(64, 8, 1), 256, 0, stream>>>(gf, gf, MROWS, DMODEL, DMODEL);
    }
}

// Round 8
// 212.794 us; speedup vs baseline: 1.6487x; 1.6487x over previous
//
#include <hip/hip_runtime.h>
#include <stdint.h>

#define DMODEL 1024
#define NHEAD 16
#define DH 64
#define BB 4
#define SS 2048
#define MROWS (BB * SS)   // 8192

typedef __bf16 bfx8 __attribute__((ext_vector_type(8)));
typedef float f32x4 __attribute__((ext_vector_type(4)));
typedef float fvec4 __attribute__((ext_vector_type(4)));
typedef int i32x4 __attribute__((ext_vector_type(4)));
typedef unsigned short u16x8 __attribute__((ext_vector_type(8)));
typedef unsigned short u16x4 __attribute__((ext_vector_type(4)));

__device__ __forceinline__ unsigned short f2bf(float f) {
    union { float f; unsigned int u; } v; v.f = f;
    unsigned int r = v.u + 0x7FFFu + ((v.u >> 16) & 1u);
    return (unsigned short)(r >> 16);
}

// packed fp32x2 -> bf16x2 (RNE), single HW instruction
__device__ __forceinline__ unsigned int cvtpk(float lo, float hi) {
    unsigned int r;
    asm("v_cvt_pk_bf16_f32 %0, %1, %2" : "=v"(r) : "v"(lo), "v"(hi));
    return r;
}

// async global->LDS, 16B per lane. LDS dest must be linear: wave base + lane*16.
typedef __attribute__((address_space(1))) const void gas_t;
typedef __attribute__((address_space(3))) void las_t;
__device__ __forceinline__ void gload_lds16(const void* g, void* l) {
    __builtin_amdgcn_global_load_lds((gas_t*)g, (las_t*)l, 16, 0, 0);
}

// K-row permutation for swapped-QK in-register P trick.
// i bits [nf1 nf0 lg1 lg0 r1 r0] -> sigma bits [nf1 lg1 lg0 nf0 r1 r0]
__device__ __forceinline__ int sigma_k(int i) {
    return (i & 0x20) | ((i & 0x0C) << 1) | ((i & 0x10) >> 2) | (i & 3);
}

// ---------------------------------------------------------------------------
// fp32 -> bf16 convert for q,k,v in one launch (blockIdx.y selects tensor)
// ---------------------------------------------------------------------------
__global__ void cvt3_kernel(const float* __restrict__ s0, const float* __restrict__ s1,
                            const float* __restrict__ s2,
                            unsigned short* __restrict__ d0, unsigned short* __restrict__ d1,
                            unsigned short* __restrict__ d2, int n8)
{
    const float* s = (blockIdx.y == 0) ? s0 : (blockIdx.y == 1) ? s1 : s2;
    unsigned short* d = (blockIdx.y == 0) ? d0 : (blockIdx.y == 1) ? d1 : d2;
    int i = blockIdx.x * blockDim.x + threadIdx.x;
    if (i >= n8) return;
    fvec4 a = *reinterpret_cast<const fvec4*>(&s[(size_t)i * 8]);
    fvec4 b = *reinterpret_cast<const fvec4*>(&s[(size_t)i * 8 + 4]);
    u16x8 o;
    #pragma unroll
    for (int j = 0; j < 4; ++j) { o[j] = f2bf(a[j]); o[j + 4] = f2bf(b[j]); }
    *reinterpret_cast<u16x8*>(&d[(size_t)i * 8]) = o;
}

// ---------------------------------------------------------------------------
// Transpose + convert: Wt[n][k] (bf16) = W[k][n] (fp32). 64x64 tiles.
// blockIdx.z selects which weight.
// ---------------------------------------------------------------------------
__global__ void transpose_cvt3_kernel(const float* __restrict__ W0, unsigned short* __restrict__ T0,
                                      const float* __restrict__ W1, unsigned short* __restrict__ T1,
                                      const float* __restrict__ W2, unsigned short* __restrict__ T2)
{
    const float* W = (blockIdx.z == 0) ? W0 : (blockIdx.z == 1) ? W1 : W2;
    unsigned short* Wt = (blockIdx.z == 0) ? T0 : (blockIdx.z == 1) ? T1 : T2;
    __shared__ unsigned short t[64][72];
    const int tid = threadIdx.x;
    const int r0 = blockIdx.y * 64, c0 = blockIdx.x * 64;
    #pragma unroll
    for (int i = 0; i < 4; ++i) {
        int idx = tid + i * 256;
        int r = idx >> 4, c4 = idx & 15;
        fvec4 v = *reinterpret_cast<const fvec4*>(&W[(size_t)(r0 + r) * DMODEL + c0 + c4 * 4]);
        #pragma unroll
        for (int j = 0; j < 4; ++j) t[c4 * 4 + j][r] = f2bf(v[j]);
    }
    __syncthreads();
    #pragma unroll
    for (int i = 0; i < 2; ++i) {
        int idx = tid + i * 256;
        int r = idx >> 3, c8 = idx & 7;
        u16x8 v = *reinterpret_cast<const u16x8*>(&t[r][c8 * 8]);
        *reinterpret_cast<u16x8*>(&Wt[(size_t)(c0 + r) * DMODEL + r0 + c8 * 8]) = v;
    }
}

// ---------------------------------------------------------------------------
// GEMM: out = A @ Bt^T + bias; bf16 in via global_load_lds.
// 128x128 tile, BK=64, 4 waves, 32 MFMA/k-step. blockIdx.z picks arg set.
// mode: 0 = bf16 row-major out, 2 = fp32 row-major out,
//       3 = bf16 Vt-layout out: O[((b*16+h)*64+d)*2048 + s] (per-head V^T)
// ---------------------------------------------------------------------------
struct GArg {
    const unsigned short* A;
    const unsigned short* Bt;
    const float* bias;
    void* O;
    float osc;
    int mode;
};

__global__ __launch_bounds__(256, 2)
void gemm_kernel(GArg g0, GArg g1, int M, int N, int K)
{
    const GArg g = blockIdx.z ? g1 : g0;
    __shared__ unsigned short sA[128 * 64];
    __shared__ unsigned short sB[128 * 64];
    const int tid  = threadIdx.x;
    const int lane = tid & 63;
    const int wave = tid >> 6;
    const int wm = (wave >> 1) * 64, wn = (wave & 1) * 64;
    const int m0 = blockIdx.x * 128, n0 = blockIdx.y * 128;
    const int lr = lane & 15;
    const int lg = lane >> 4;

    f32x4 acc[4][4] = {};

    for (int kk0 = 0; kk0 < K; kk0 += 64) {
        __syncthreads();
        #pragma unroll
        for (int i = 0; i < 4; ++i) {
            int c = tid + i * 256;
            int row = c >> 3, col8 = c & 7;
            gload_lds16(&g.A[(size_t)(m0 + row) * K + kk0 + col8 * 8], &sA[c * 8]);
        }
        #pragma unroll
        for (int i = 0; i < 4; ++i) {
            int c = tid + i * 256;
            int row = c >> 3, col8 = c & 7;
            gload_lds16(&g.Bt[(size_t)(n0 + row) * K + kk0 + col8 * 8], &sB[c * 8]);
        }
        __syncthreads();

        bfx8 af[4][2], bfr[4][2];
        #pragma unroll
        for (int m = 0; m < 4; ++m)
            #pragma unroll
            for (int kk = 0; kk < 2; ++kk)
                af[m][kk] = *reinterpret_cast<const bfx8*>(
                    &sA[(wm + m * 16 + lr) * 64 + kk * 32 + lg * 8]);
        #pragma unroll
        for (int n = 0; n < 4; ++n)
            #pragma unroll
            for (int kk = 0; kk < 2; ++kk)
                bfr[n][kk] = *reinterpret_cast<const bfx8*>(
                    &sB[(wn + n * 16 + lr) * 64 + kk * 32 + lg * 8]);
        #pragma unroll
        for (int kk = 0; kk < 2; ++kk)
            #pragma unroll
            for (int m = 0; m < 4; ++m)
                #pragma unroll
                for (int n = 0; n < 4; ++n)
                    acc[m][n] = __builtin_amdgcn_mfma_f32_16x16x32_bf16(
                        af[m][kk], bfr[n][kk], acc[m][n], 0, 0, 0);
    }

    #pragma unroll
    for (int n = 0; n < 4; ++n) {
        int col = n0 + wn + n * 16 + lr;
        float bv = g.bias[col];
        #pragma unroll
        for (int m = 0; m < 4; ++m) {
            int rowb = m0 + wm + m * 16 + lg * 4;
            float val[4];
            #pragma unroll
            for (int r = 0; r < 4; ++r) val[r] = (acc[m][n][r] + bv) * g.osc;
            if (g.mode == 0) {
                #pragma unroll
                for (int r = 0; r < 4; ++r)
                    ((unsigned short*)g.O)[(size_t)(rowb + r) * N + col] = f2bf(val[r]);
            } else if (g.mode == 2) {
                #pragma unroll
                for (int r = 0; r < 4; ++r)
                    ((float*)g.O)[(size_t)(rowb + r) * N + col] = val[r];
            } else {
                // Vt layout: rows rowb..rowb+3 are consecutive s in one batch
                int bq = rowb >> 11, s = rowb & 2047;
                int hh = col >> 6, d = col & 63;
                u16x4 pk;
                #pragma unroll
                for (int r = 0; r < 4; ++r) pk[r] = f2bf(val[r]);
                size_t idx = ((size_t)(bq * 16 + hh) * 64 + d) * 2048 + s;
                *reinterpret_cast<u16x4*>(&((unsigned short*)g.O)[idx]) = pk;
            }
        }
    }
}

// ---------------------------------------------------------------------------
// Flash-style causal attention (R4 structure + s_setprio on MFMA clusters).
// Q pre-scaled by 1/sqrt(2048)*log2(e). Q,K: [B*S][H*DH] bf16; Vt: [B*H][DH][S].
// Grid: x = B*H (64), y = 16 q-tiles of 128 (heavy-first). 4 waves x 32 q-rows.
// P stays in registers: lane owns q=lane&15; sigma-permuted K staging makes the
// 16 in-lane score values land exactly at the PV A-fragment slots.
// ---------------------------------------------------------------------------
__global__ __launch_bounds__(256, 2)
void attn_kernel(const unsigned short* __restrict__ Q,
                 const unsigned short* __restrict__ K,
                 const unsigned short* __restrict__ Vt,
                 unsigned short* __restrict__ C)
{
    __shared__ unsigned short sK[64][72];        // row i = K row k0+sigma(i), [k][d]
    __shared__ unsigned short sVt[64][72];       // [d][k] natural k order

    const int tid  = threadIdx.x;
    const int lane = tid & 63;
    const int wave = tid >> 6;
    const int lr = lane & 15, lg = lane >> 4;
    const int bh = blockIdx.x;
    const int qt = (int)(gridDim.y - 1) - (int)blockIdx.y;   // heavy tiles first
    const int b = bh >> 4, h = bh & 15;
    const int q0 = qt * 128;
    const size_t rowbase = (size_t)b * SS;
    const int hcol = h * DH;

    // staging coords (constant per thread)
    const int srow = tid >> 3, sc8 = tid & 7;
    const int sig0 = sigma_k(srow), sig1 = sigma_k(srow + 32);

    // Q fragments: 2 m-frags x 2 d-chunks (B-operand of swapped mfma)
    bfx8 aq[2][2];
    #pragma unroll
    for (int m = 0; m < 2; ++m) {
        int qr = q0 + wave * 32 + m * 16 + lr;
        const unsigned short* p = &Q[(rowbase + qr) * DMODEL + hcol + lg * 8];
        aq[m][0] = *reinterpret_cast<const bfx8*>(p);
        aq[m][1] = *reinterpret_cast<const bfx8*>(p + 32);
    }

    float m_run[2] = {0.f, 0.f};          // per-lane (q = lr) running max, exp2 dom
    f32x4 l4[2] = {};                     // per-lane partial sum-of-P (vector)
    f32x4 acc_o[2][4] = {};
    bool mz = true;
    const int qmax_wave = q0 + wave * 32 + 31;
    const int ntiles = 2 * qt + 2;

    for (int t = 0; t < ntiles; ++t) {
        const int k0 = t * 64;
        __syncthreads();
        // ---- stage K (sigma-permuted rows) and Vt (natural)
        *reinterpret_cast<u16x8*>(&sK[srow][sc8 * 8]) =
            *reinterpret_cast<const u16x8*>(
                &K[(rowbase + k0 + sig0) * DMODEL + hcol + sc8 * 8]);
        *reinterpret_cast<u16x8*>(&sK[srow + 32][sc8 * 8]) =
            *reinterpret_cast<const u16x8*>(
                &K[(rowbase + k0 + sig1) * DMODEL + hcol + sc8 * 8]);
        *reinterpret_cast<u16x8*>(&sVt[srow][sc8 * 8]) =
            *reinterpret_cast<const u16x8*>(
                &Vt[((size_t)bh * DH + srow) * SS + k0 + sc8 * 8]);
        *reinterpret_cast<u16x8*>(&sVt[srow + 32][sc8 * 8]) =
            *reinterpret_cast<const u16x8*>(
                &Vt[((size_t)bh * DH + srow + 32) * SS + k0 + sc8 * 8]);
        __syncthreads();
        if (k0 > qmax_wave) continue;     // fully masked for this wave

        // ---- S^T = K_perm @ Q : sc[m][nf][r] = S[q=lr][k = k0+sig(nf*16+lg*4+r)]
        f32x4 sc[2][4];
        __builtin_amdgcn_s_setprio(1);
        #pragma unroll
        for (int nf = 0; nf < 4; ++nf) {
            bfx8 ak0 = *reinterpret_cast<const bfx8*>(&sK[nf * 16 + lr][lg * 8]);
            bfx8 ak1 = *reinterpret_cast<const bfx8*>(&sK[nf * 16 + lr][32 + lg * 8]);
            #pragma unroll
            for (int m = 0; m < 2; ++m) {
                f32x4 s = {0.f, 0.f, 0.f, 0.f};
                s = __builtin_amdgcn_mfma_f32_16x16x32_bf16(ak0, aq[m][0], s, 0, 0, 0);
                s = __builtin_amdgcn_mfma_f32_16x16x32_bf16(ak1, aq[m][1], s, 0, 0, 0);
                sc[m][nf] = s;
            }
        }
        __builtin_amdgcn_s_setprio(0);
        // ---- causal mask: k = kb + r, q = qrow
        #pragma unroll
        for (int m = 0; m < 2; ++m) {
            if (k0 + 63 > q0 + wave * 32 + m * 16) {
                int qrow = q0 + wave * 32 + m * 16 + lr;
                #pragma unroll
                for (int nf = 0; nf < 4; ++nf) {
                    int kb = k0 + ((nf >> 1) << 5) + (lg << 3) + ((nf & 1) << 2);
                    #pragma unroll
                    for (int r = 0; r < 4; ++r)
                        if (kb + r > qrow) sc[m][nf][r] = -3.0e38f;
                }
            }
        }
        // ---- softmax: defer-max fast path (exp2 domain, max stays 0)
        f32x4 mx4 = sc[0][0];
        #pragma unroll
        for (int m = 0; m < 2; ++m)
            #pragma unroll
            for (int nf = 0; nf < 4; ++nf)
                #pragma unroll
                for (int r = 0; r < 4; ++r) mx4[r] = fmaxf(mx4[r], sc[m][nf][r]);
        float pmax = fmaxf(fmaxf(mx4[0], mx4[1]), fmaxf(mx4[2], mx4[3]));
        if (mz && __all(pmax <= 8.0f)) {
            #pragma unroll
            for (int m = 0; m < 2; ++m)
                #pragma unroll
                for (int nf = 0; nf < 4; ++nf) {
                    #pragma unroll
                    for (int r = 0; r < 4; ++r)
                        sc[m][nf][r] = __builtin_exp2f(sc[m][nf][r]);
                    l4[m] += sc[m][nf];
                }
        } else {
            mz = false;
            #pragma unroll
            for (int m = 0; m < 2; ++m) {
                float mx = -3.0e38f;
                #pragma unroll
                for (int nf = 0; nf < 4; ++nf)
                    #pragma unroll
                    for (int r = 0; r < 4; ++r) mx = fmaxf(mx, sc[m][nf][r]);
                mx = fmaxf(mx, __shfl_xor(mx, 16, 64));
                mx = fmaxf(mx, __shfl_xor(mx, 32, 64));
                float mnew = fmaxf(m_run[m], mx);
                float fs = __builtin_exp2f(m_run[m] - mnew);
                m_run[m] = mnew;
                f32x4 ps = {0.f, 0.f, 0.f, 0.f};
                #pragma unroll
                for (int nf = 0; nf < 4; ++nf) {
                    #pragma unroll
                    for (int r = 0; r < 4; ++r)
                        sc[m][nf][r] = __builtin_exp2f(sc[m][nf][r] - mnew);
                    ps += sc[m][nf];
                }
                #pragma unroll
                for (int r = 0; r < 4; ++r) l4[m][r] = l4[m][r] * fs + ps[r];
                #pragma unroll
                for (int r = 0; r < 4; ++r) {
                    float fsa = __shfl(fs, lg * 4 + r, 64);
                    #pragma unroll
                    for (int d = 0; d < 4; ++d) acc_o[m][d][r] *= fsa;
                }
            }
        }
        // ---- pack P (in-register!) and accumulate P @ V
        #pragma unroll
        for (int h2 = 0; h2 < 2; ++h2) {
            union { i32x4 i; bfx8 b; } pa[2];
            #pragma unroll
            for (int m = 0; m < 2; ++m) {
                pa[m].i[0] = cvtpk(sc[m][2 * h2][0],     sc[m][2 * h2][1]);
                pa[m].i[1] = cvtpk(sc[m][2 * h2][2],     sc[m][2 * h2][3]);
                pa[m].i[2] = cvtpk(sc[m][2 * h2 + 1][0], sc[m][2 * h2 + 1][1]);
                pa[m].i[3] = cvtpk(sc[m][2 * h2 + 1][2], sc[m][2 * h2 + 1][3]);
            }
            __builtin_amdgcn_s_setprio(1);
            #pragma unroll
            for (int d = 0; d < 4; ++d) {
                bfx8 bv0 = *reinterpret_cast<const bfx8*>(&sVt[d * 16 + lr][h2 * 32 + lg * 8]);
                acc_o[0][d] = __builtin_amdgcn_mfma_f32_16x16x32_bf16(pa[0].b, bv0, acc_o[0][d], 0, 0, 0);
                acc_o[1][d] = __builtin_amdgcn_mfma_f32_16x16x32_bf16(pa[1].b, bv0, acc_o[1][d], 0, 0, 0);
            }
            __builtin_amdgcn_s_setprio(0);
        }
    }

    // ---- epilogue: l = hsum(l4) reduced across lg group; broadcast to acc rows
    #pragma unroll
    for (int m = 0; m < 2; ++m) {
        float l = (l4[m][0] + l4[m][1]) + (l4[m][2] + l4[m][3]);
        l += __shfl_xor(l, 16, 64);
        l += __shfl_xor(l, 32, 64);
        float linv = 1.0f / l;                   // valid at q = lr
        float linva[4];
        #pragma unroll
        for (int r = 0; r < 4; ++r) linva[r] = __shfl(linv, lg * 4 + r, 64);
        const int qrb = q0 + wave * 32 + m * 16 + lg * 4;
        #pragma unroll
        for (int d = 0; d < 4; ++d) {
            int col = hcol + d * 16 + lr;
            #pragma unroll
            for (int r = 0; r < 4; ++r)
                C[(rowbase + qrb + r) * DMODEL + col] = f2bf(acc_o[m][d][r] * linva[r]);
        }
    }
}

// ---------------------------------------------------------------------------
extern "C" void kernel_launch(void* const* d_in, const int* in_sizes, int n_in,
                              void* d_out, int out_size, void* d_ws, size_t ws_size,
                              hipStream_t stream)
{
    const float* q  = (const float*)d_in[0];
    const float* k  = (const float*)d_in[1];
    const float* v  = (const float*)d_in[2];
    const float* Wq = (const float*)d_in[3];
    const float* bq = (const float*)d_in[4];
    const float* Wk = (const float*)d_in[5];
    const float* bk = (const float*)d_in[6];
    const float* Wv = (const float*)d_in[7];
    const float* bv = (const float*)d_in[8];
    const float* Wf = (const float*)d_in[9];
    const float* bf = (const float*)d_in[10];

    unsigned short* ws = (unsigned short*)d_ws;
    const size_t SZ = (size_t)MROWS * DMODEL;        // 8388608 elems
    unsigned short* ws0 = ws;                        // qb16 -> Vt -> (dead)
    unsigned short* ws1 = ws + SZ;                   // kb16 -> Cb
    unsigned short* ws2 = ws + 2 * SZ;               // vb16 -> WfT
    unsigned short* ws3 = ws + 3 * SZ;               // Kproj

    unsigned short* scr = (unsigned short*)d_out;    // d_out as scratch (16M ushorts)
    unsigned short* WqT = scr;                       // [0,1M)
    unsigned short* WkT = scr + 1048576;             // [1M,2M)
    unsigned short* WvT = scr + 2097152;             // [2M,3M)
    unsigned short* Qb  = scr + 4194304;             // [4M,12M)

    const float qscale = 0.02209708691207961f * 1.44269504088896341f;

    // 1. q,k,v fp32 -> bf16
    const int n8 = (int)(SZ / 8);
    cvt3_kernel<<<dim3((n8 + 255) / 256, 3), 256, 0, stream>>>(q, k, v, ws0, ws1, ws2, n8);

    // 2. Wq/Wk/Wv transpose
    transpose_cvt3_kernel<<<dim3(16, 16, 3), 256, 0, stream>>>(Wq, WqT, Wk, WkT, Wv, WvT);

    // 3. Q and K projections (Q pre-scaled into exp2 domain)
    {
        GArg gq{ws0, WqT, bq, Qb,  qscale, 0};
        GArg gk{ws1, WkT, bk, ws3, 1.0f,   0};
        gemm_kernel<<<dim3(64, 8, 2), 256, 0, stream>>>(gq, gk, MROWS, DMODEL, DMODEL);
    }
    // 4. V projection directly into Vt layout -> ws0 (qb16 dead)
    {
        GArg gv{ws2, WvT, bv, ws0, 1.0f, 3};
        gemm_kernel<<<dim3(64, 8, 1), 256, 0, stream>>>(gv, gv, MROWS, DMODEL, DMODEL);
    }
    // 5. Wf transpose -> ws2 (vb16 dead)
    transpose_cvt3_kernel<<<dim3(16, 16, 1), 256, 0, stream>>>(Wf, ws2, Wf, ws2, Wf, ws2);

    // 6. attention: Qb, Kproj(ws3), Vt(ws0) -> Cb(ws1)  (kb16 dead)
    attn_kernel<<<dim3(BB * NHEAD, SS / 128), 256, 0, stream>>>(Qb, ws3, ws0, ws1);

    // 7. output projection: Cb @ WfT + bf -> d_out fp32 (scratch regions dead)
    {
        GArg gf{ws1, ws2, bf, (float*)d_out, 1.0f, 2};
        gemm_kernel<<<dim3(64, 8, 1), 256, 0, stream>>>(gf, gf, MROWS, DMODEL, DMODEL);
    }
}